// Round 4
// baseline (38.347 us; speedup 1.0000x reference)
//
#include <hip/hip_runtime.h>

#define HD 1152          // hidden size
#define SQ 4096          // seq len
#define NB 256           // output bins (L)
#define BT 8             // batch
#define KK 4             // pool kernel size

// One block per (batch, bin-pair). 512 threads; each thread owns 8 consecutive
// tokens (block covers all 4096 tokens of the batch).
//   phase 1: per-batch max_x reduce from registers
//   phase 2: flat ids in registers; per-thread 8-bit match masks for BOTH bins;
//            one packed (16+16) prefix-scan; stable compaction into list[]
//            (bin A at offset 0, bin B at offset totalA)
//   phase 3: threads 0-255 gather-sum bin A's rows, threads 256-511 bin B's,
//            float4 loads, 4-deep unroll
__global__ void __launch_bounds__(512, 8) k_pool(const int* __restrict__ pos,
                                                 const float* __restrict__ hs,
                                                 float* __restrict__ out,
                                                 float* __restrict__ mask) {
    const int bl = blockIdx.x;            // b*128 + pair
    const int b = bl >> 7;
    const unsigned la = (unsigned)((bl & 127) * 2);   // bins la, la+1
    const int tid = threadIdx.x;
    const int wv = tid >> 6, lane = tid & 63;

    __shared__ unsigned short list[SQ];
    __shared__ unsigned wsum[8];
    __shared__ int smax[8];

    // each thread owns tokens [8*tid, 8*tid+8): 16 ints = 4 int4
    const int tokbase = tid * 8;
    const int4* pp = (const int4*)(pos + (size_t)b * SQ * 2) + tid * 4;
    int4 q[4];
    #pragma unroll
    for (int j = 0; j < 4; ++j) q[j] = pp[j];   // {x0,y0,x1,y1} tokens 2j,2j+1

    // ---- phase 1: block max of raw x (== max of clamped x when any >= 0)
    int mx = -1;
    #pragma unroll
    for (int j = 0; j < 4; ++j) mx = max(mx, max(q[j].x, q[j].z));
    #pragma unroll
    for (int off = 32; off > 0; off >>= 1)
        mx = max(mx, __shfl_down(mx, off, 64));
    if (lane == 0) smax[wv] = mx;
    __syncthreads();
    int mxa = smax[0];
    #pragma unroll
    for (int w = 1; w < 8; ++w) mxa = max(mxa, smax[w]);
    const int mxq = (mxa + 1) / KK;       // (max_x) // k, correct for all-pad too

    // ---- phase 2: flat ids + dual match masks + packed compaction
    unsigned mA = 0, mB = 0;
    #pragma unroll
    for (int j = 0; j < 4; ++j) {
        int x0 = q[j].x, y0 = q[j].y, x1 = q[j].z, y1 = q[j].w;
        unsigned f0 = (unsigned)((max(x0, 0) >> 2) + mxq * (max(y0, 0) >> 2));
        unsigned f1 = (unsigned)((max(x1, 0) >> 2) + mxq * (max(y1, 0) >> 2));
        bool p0 = (x0 == -1) && (y0 == -1);
        bool p1 = (x1 == -1) && (y1 == -1);
        if (!p0) {
            if (f0 == la)     mA |= 1u << (2 * j);
            if (f0 == la + 1) mB |= 1u << (2 * j);
        }
        if (!p1) {
            if (f1 == la)     mA |= 1u << (2 * j + 1);
            if (f1 == la + 1) mB |= 1u << (2 * j + 1);
        }
    }
    const unsigned cntP = (unsigned)__popc(mA) | ((unsigned)__popc(mB) << 16);

    unsigned pre = cntP;                  // packed inclusive wave prefix
    #pragma unroll
    for (int off = 1; off < 64; off <<= 1) {
        unsigned n = (unsigned)__shfl_up((int)pre, off, 64);
        if (lane >= off) pre += n;
    }
    if (lane == 63) wsum[wv] = pre;
    __syncthreads();

    unsigned woff = 0, tot = 0;
    #pragma unroll
    for (int w = 0; w < 8; ++w) {
        unsigned v = wsum[w];
        if (w < wv) woff += v;
        tot += v;
    }
    const unsigned exclP = woff + pre - cntP;            // packed exclusive prefix
    const int totalA = (int)(tot & 0xFFFFu);
    const int totalB = (int)(tot >> 16);

    // scatter (stable, deterministic order)
    {
        int r = (int)(exclP & 0xFFFFu);
        unsigned m = mA;
        while (m) { int j = __ffs(m) - 1; m &= m - 1; list[r++] = (unsigned short)(tokbase + j); }
        r = totalA + (int)(exclP >> 16);
        m = mB;
        while (m) { int j = __ffs(m) - 1; m &= m - 1; list[r++] = (unsigned short)(tokbase + j); }
    }
    __syncthreads();

    // ---- phase 3: half-block gather. waves 0-3 -> bin A, waves 4-7 -> bin B
    const int half = tid >> 8;            // 0 or 1
    const int t = tid & 255;
    const unsigned short* lst = list + (half ? totalA : 0);
    const int cnt = half ? totalB : totalA;
    const float* hb = hs + (size_t)b * SQ * HD;

    float4 a0 = make_float4(0.f, 0.f, 0.f, 0.f);
    float4 a1 = make_float4(0.f, 0.f, 0.f, 0.f);
    int i = 0;
    for (; i + 3 < cnt; i += 4) {
        const float4* r0 = (const float4*)(hb + (size_t)lst[i]     * HD);
        const float4* r1 = (const float4*)(hb + (size_t)lst[i + 1] * HD);
        const float4* r2 = (const float4*)(hb + (size_t)lst[i + 2] * HD);
        const float4* r3 = (const float4*)(hb + (size_t)lst[i + 3] * HD);
        float4 v0 = r0[t], v1 = r1[t], v2 = r2[t], v3 = r3[t];
        a0.x += v0.x + v1.x + v2.x + v3.x;
        a0.y += v0.y + v1.y + v2.y + v3.y;
        a0.z += v0.z + v1.z + v2.z + v3.z;
        a0.w += v0.w + v1.w + v2.w + v3.w;
        if (t < HD / 4 - 256) {
            float4 u0 = r0[256 + t], u1 = r1[256 + t];
            float4 u2 = r2[256 + t], u3 = r3[256 + t];
            a1.x += u0.x + u1.x + u2.x + u3.x;
            a1.y += u0.y + u1.y + u2.y + u3.y;
            a1.z += u0.z + u1.z + u2.z + u3.z;
            a1.w += u0.w + u1.w + u2.w + u3.w;
        }
    }
    for (; i < cnt; ++i) {
        const float4* r0 = (const float4*)(hb + (size_t)lst[i] * HD);
        float4 v0 = r0[t];
        a0.x += v0.x; a0.y += v0.y; a0.z += v0.z; a0.w += v0.w;
        if (t < HD / 4 - 256) {
            float4 u0 = r0[256 + t];
            a1.x += u0.x; a1.y += u0.y; a1.z += u0.z; a1.w += u0.w;
        }
    }

    const float scale = 2.1213203435596424f;   // sqrt(1152) / 16
    const int orow = (b << 8) + (int)la + half;
    float4* o = (float4*)(out + (size_t)orow * HD);
    a0.x *= scale; a0.y *= scale; a0.z *= scale; a0.w *= scale;
    o[t] = a0;
    if (t < HD / 4 - 256) {
        a1.x *= scale; a1.y *= scale; a1.z *= scale; a1.w *= scale;
        o[256 + t] = a1;
    }
    if (t == 0) mask[orow] = (cnt > 0) ? 1.0f : 0.0f;
}

extern "C" void kernel_launch(void* const* d_in, const int* in_sizes, int n_in,
                              void* d_out, int out_size, void* d_ws, size_t ws_size,
                              hipStream_t stream) {
    const float* hs = (const float*)d_in[0];
    const int* pos = (const int*)d_in[1];
    float* out = (float*)d_out;                        // pooled [8,256,1152]
    float* mask = out + (size_t)BT * NB * HD;          // mask   [8,256]

    k_pool<<<BT * NB / 2, 512, 0, stream>>>(pos, hs, out, mask);
}

// Round 5
// 34.850 us; speedup vs baseline: 1.1003x; 1.1003x over previous
//
#include <hip/hip_runtime.h>

#define HD 1152          // hidden size
#define SQ 4096          // seq len
#define NB 256           // output bins (L)
#define BT 8             // batch
#define KK 4             // pool kernel size

// One block per (b, bin). Each of the 256 threads owns 16 consecutive tokens
// (block covers the batch's full 4096 tokens exactly).
//   phase 1: per-batch max_x reduce from registers
//   phase 2: flat bin ids in registers, 16-bit match mask, wave prefix-sum
//            compaction into an LDS row-offset list (deterministic order)
//   phase 3: gather-sum matching rows. 288 float4/row split wave-balanced:
//            thread t reads f4 col t; threads with (t&7)==7 also read col
//            256+(t>>3)  -> every wave does 64+8 f4 per row (uniform).
__global__ void __launch_bounds__(256, 6) k_pool(const int* __restrict__ pos,
                                                 const float* __restrict__ hs,
                                                 float* __restrict__ out,
                                                 float* __restrict__ mask) {
    int bl = blockIdx.x;          // b*NB + l
    int b = bl >> 8;
    unsigned l = (unsigned)(bl & (NB - 1));
    int tid = threadIdx.x;
    int wv = tid >> 6, lane = tid & 63;

    __shared__ unsigned list[SQ];   // element offsets (token*HD)
    __shared__ int wcnt[4];
    __shared__ int smax[4];

    // each thread owns tokens [16*tid, 16*tid+16): 32 ints = 8 int4
    const int tokbase = tid * 16;
    const int4* pp = (const int4*)(pos + (size_t)b * SQ * 2) + tid * 8;
    int4 q[8];
    #pragma unroll
    for (int j = 0; j < 8; ++j) q[j] = pp[j];   // {x0,y0,x1,y1} tokens 2j,2j+1

    // ---- phase 1: block max of raw x (clamp happens after: max>=0 iff any valid)
    int mx = -1;
    #pragma unroll
    for (int j = 0; j < 8; ++j) mx = max(mx, max(q[j].x, q[j].z));
    if (mx < 0) mx = 0;
    #pragma unroll
    for (int off = 32; off > 0; off >>= 1)
        mx = max(mx, __shfl_down(mx, off, 64));
    if (lane == 0) smax[wv] = mx;
    __syncthreads();
    const int mxq = (max(max(smax[0], smax[1]), max(smax[2], smax[3])) + 1) / KK;

    // ---- phase 2: flat ids + match mask + compaction
    unsigned m16 = 0;
    #pragma unroll
    for (int j = 0; j < 8; ++j) {
        int x0 = q[j].x, y0 = q[j].y, x1 = q[j].z, y1 = q[j].w;
        unsigned f0 = (unsigned)((max(x0, 0) >> 2) + mxq * (max(y0, 0) >> 2));
        unsigned f1 = (unsigned)((max(x1, 0) >> 2) + mxq * (max(y1, 0) >> 2));
        bool p0 = (x0 == -1) && (y0 == -1);
        bool p1 = (x1 == -1) && (y1 == -1);
        if (!p0 && f0 == l) m16 |= 1u << (2 * j);
        if (!p1 && f1 == l) m16 |= 1u << (2 * j + 1);
    }
    int cnt = __popc(m16);

    int pre = cnt;                      // inclusive wave prefix
    #pragma unroll
    for (int off = 1; off < 64; off <<= 1) {
        int n = __shfl_up(pre, off, 64);
        if (lane >= off) pre += n;
    }
    if (lane == 63) wcnt[wv] = pre;
    int excl = pre - cnt;
    __syncthreads();

    int woff = 0;
    #pragma unroll
    for (int v = 0; v < 4; ++v) if (v < wv) woff += wcnt[v];
    int total = wcnt[0] + wcnt[1] + wcnt[2] + wcnt[3];

    int r = woff + excl;
    unsigned m = m16;
    while (m) {
        int j = __ffs(m) - 1;
        m &= m - 1;
        list[r++] = (unsigned)(tokbase + j) * HD;
    }
    __syncthreads();

    // ---- phase 3: wave-balanced gather-sum
    const bool xtra = (tid & 7) == 7;
    const int ec = 256 + (tid >> 3);    // extra f4 col for xtra threads
    float4 a0 = make_float4(0.f, 0.f, 0.f, 0.f);
    float4 a1 = make_float4(0.f, 0.f, 0.f, 0.f);
    const float* hb = hs + (size_t)b * SQ * HD;
    int i = 0;
    for (; i + 3 < total; i += 4) {
        const float4* r0 = (const float4*)(hb + list[i]);
        const float4* r1 = (const float4*)(hb + list[i + 1]);
        const float4* r2 = (const float4*)(hb + list[i + 2]);
        const float4* r3 = (const float4*)(hb + list[i + 3]);
        float4 v0 = r0[tid], v1 = r1[tid], v2 = r2[tid], v3 = r3[tid];
        a0.x += v0.x + v1.x + v2.x + v3.x;
        a0.y += v0.y + v1.y + v2.y + v3.y;
        a0.z += v0.z + v1.z + v2.z + v3.z;
        a0.w += v0.w + v1.w + v2.w + v3.w;
        if (xtra) {
            float4 u0 = r0[ec], u1 = r1[ec], u2 = r2[ec], u3 = r3[ec];
            a1.x += u0.x + u1.x + u2.x + u3.x;
            a1.y += u0.y + u1.y + u2.y + u3.y;
            a1.z += u0.z + u1.z + u2.z + u3.z;
            a1.w += u0.w + u1.w + u2.w + u3.w;
        }
    }
    for (; i < total; ++i) {
        const float4* r0 = (const float4*)(hb + list[i]);
        float4 v0 = r0[tid];
        a0.x += v0.x; a0.y += v0.y; a0.z += v0.z; a0.w += v0.w;
        if (xtra) {
            float4 u0 = r0[ec];
            a1.x += u0.x; a1.y += u0.y; a1.z += u0.z; a1.w += u0.w;
        }
    }

    const float scale = 2.1213203435596424f;   // sqrt(1152) / 16
    float4* o = (float4*)(out + (size_t)bl * HD);
    a0.x *= scale; a0.y *= scale; a0.z *= scale; a0.w *= scale;
    o[tid] = a0;
    if (xtra) {
        a1.x *= scale; a1.y *= scale; a1.z *= scale; a1.w *= scale;
        o[ec] = a1;
    }
    if (tid == 0) mask[bl] = (total > 0) ? 1.0f : 0.0f;
}

extern "C" void kernel_launch(void* const* d_in, const int* in_sizes, int n_in,
                              void* d_out, int out_size, void* d_ws, size_t ws_size,
                              hipStream_t stream) {
    const float* hs = (const float*)d_in[0];
    const int* pos = (const int*)d_in[1];
    float* out = (float*)d_out;                        // pooled [8,256,1152]
    float* mask = out + (size_t)BT * NB * HD;          // mask   [8,256]

    k_pool<<<BT * NB, 256, 0, stream>>>(pos, hs, out, mask);
}

// Round 6
// 32.406 us; speedup vs baseline: 1.1833x; 1.0754x over previous
//
#include <hip/hip_runtime.h>

#define HD 1152          // hidden size
#define SQ 4096          // seq len
#define NB 256           // output bins (L)
#define BT 8             // batch
#define KK 4             // pool kernel size

// One block per (batch, bin-pair). 256 threads; each thread owns 16 tokens
// (block covers the batch's full 4096 tokens exactly).
//   phase 1: per-batch max_x reduce from registers
//   phase 2: flat ids in registers; dual 16-bit match masks (bins 2p, 2p+1);
//            one packed (16|16) wave prefix-scan; stable compaction into an
//            LDS token list (bin A at 0, bin B at totalA)
//   phase 3: waves 0-1 gather bin A, waves 2-3 gather bin B. Per row of 288
//            float4: thread t (0-127) reads cols t and 128+t; t<32 also reads
//            256+t (contiguous — 1 quarter-wave vmem, round-3-proven shape).
// NOTE: no min-waves launch bound — capping VGPRs spilled this kernel twice.
__global__ void __launch_bounds__(256) k_pool(const int* __restrict__ pos,
                                              const float* __restrict__ hs,
                                              float* __restrict__ out,
                                              float* __restrict__ mask) {
    const int bl = blockIdx.x;            // b*128 + pair
    const int b = bl >> 7;
    const unsigned la = (unsigned)((bl & 127) << 1);   // bins la, la+1
    const int tid = threadIdx.x;
    const int wv = tid >> 6, lane = tid & 63;

    __shared__ unsigned short list[SQ];   // token ids; A at 0, B at totalA
    __shared__ unsigned wsum[4];
    __shared__ int smax[4];

    // each thread owns tokens [16*tid, 16*tid+16): 32 ints = 8 int4
    const int tokbase = tid * 16;
    const int4* pp = (const int4*)(pos + (size_t)b * SQ * 2) + tid * 8;
    int4 q[8];
    #pragma unroll
    for (int j = 0; j < 8; ++j) q[j] = pp[j];   // {x0,y0,x1,y1} tokens 2j,2j+1

    // ---- phase 1: block max of x (clamped; max(clamped) == clamp(max))
    int mx = -1;
    #pragma unroll
    for (int j = 0; j < 8; ++j) mx = max(mx, max(q[j].x, q[j].z));
    if (mx < 0) mx = 0;
    #pragma unroll
    for (int off = 32; off > 0; off >>= 1)
        mx = max(mx, __shfl_down(mx, off, 64));
    if (lane == 0) smax[wv] = mx;
    __syncthreads();
    const int mxq = (max(max(smax[0], smax[1]), max(smax[2], smax[3])) + 1) / KK;

    // ---- phase 2: flat ids + dual match masks + packed compaction
    unsigned mA = 0, mB = 0;
    #pragma unroll
    for (int j = 0; j < 8; ++j) {
        int x0 = q[j].x, y0 = q[j].y, x1 = q[j].z, y1 = q[j].w;
        unsigned f0 = (unsigned)((max(x0, 0) >> 2) + mxq * (max(y0, 0) >> 2));
        unsigned f1 = (unsigned)((max(x1, 0) >> 2) + mxq * (max(y1, 0) >> 2));
        bool p0 = (x0 == -1) && (y0 == -1);
        bool p1 = (x1 == -1) && (y1 == -1);
        if (!p0) {
            if (f0 == la)          mA |= 1u << (2 * j);
            else if (f0 == la + 1) mB |= 1u << (2 * j);
        }
        if (!p1) {
            if (f1 == la)          mA |= 1u << (2 * j + 1);
            else if (f1 == la + 1) mB |= 1u << (2 * j + 1);
        }
    }
    const unsigned cntP = (unsigned)__popc(mA) | ((unsigned)__popc(mB) << 16);

    unsigned pre = cntP;                  // packed inclusive wave prefix
    #pragma unroll
    for (int off = 1; off < 64; off <<= 1) {
        unsigned n = (unsigned)__shfl_up((int)pre, off, 64);
        if (lane >= off) pre += n;
    }
    if (lane == 63) wsum[wv] = pre;
    __syncthreads();

    unsigned woff = 0, tot = 0;
    #pragma unroll
    for (int w = 0; w < 4; ++w) {
        unsigned v = wsum[w];
        if (w < wv) woff += v;
        tot += v;
    }
    const unsigned exclP = woff + pre - cntP;   // packed exclusive prefix
    const int totalA = (int)(tot & 0xFFFFu);
    const int totalB = (int)(tot >> 16);

    // stable scatter (deterministic order)
    {
        int r = (int)(exclP & 0xFFFFu);
        unsigned m = mA;
        while (m) { int j = __ffs(m) - 1; m &= m - 1; list[r++] = (unsigned short)(tokbase + j); }
        r = totalA + (int)(exclP >> 16);
        m = mB;
        while (m) { int j = __ffs(m) - 1; m &= m - 1; list[r++] = (unsigned short)(tokbase + j); }
    }
    __syncthreads();

    // ---- phase 3: half-block gather (waves 0-1 -> bin A, waves 2-3 -> bin B)
    const int half = tid >> 7;            // 0 or 1
    const int t = tid & 127;
    const unsigned short* lst = list + (half ? totalA : 0);
    const int cnt = half ? totalB : totalA;
    const float* hb = hs + (size_t)b * SQ * HD;

    float4 a0 = make_float4(0.f, 0.f, 0.f, 0.f);
    float4 a1 = make_float4(0.f, 0.f, 0.f, 0.f);
    float4 a2 = make_float4(0.f, 0.f, 0.f, 0.f);
    int i = 0;
    for (; i + 3 < cnt; i += 4) {
        const float4* r0 = (const float4*)(hb + (size_t)lst[i]     * HD);
        const float4* r1 = (const float4*)(hb + (size_t)lst[i + 1] * HD);
        const float4* r2 = (const float4*)(hb + (size_t)lst[i + 2] * HD);
        const float4* r3 = (const float4*)(hb + (size_t)lst[i + 3] * HD);
        float4 v0 = r0[t], v1 = r1[t], v2 = r2[t], v3 = r3[t];
        a0.x += v0.x + v1.x + v2.x + v3.x;
        a0.y += v0.y + v1.y + v2.y + v3.y;
        a0.z += v0.z + v1.z + v2.z + v3.z;
        a0.w += v0.w + v1.w + v2.w + v3.w;
        float4 w0 = r0[128 + t], w1 = r1[128 + t], w2 = r2[128 + t], w3 = r3[128 + t];
        a1.x += w0.x + w1.x + w2.x + w3.x;
        a1.y += w0.y + w1.y + w2.y + w3.y;
        a1.z += w0.z + w1.z + w2.z + w3.z;
        a1.w += w0.w + w1.w + w2.w + w3.w;
        if (t < 32) {
            float4 u0 = r0[256 + t], u1 = r1[256 + t];
            float4 u2 = r2[256 + t], u3 = r3[256 + t];
            a2.x += u0.x + u1.x + u2.x + u3.x;
            a2.y += u0.y + u1.y + u2.y + u3.y;
            a2.z += u0.z + u1.z + u2.z + u3.z;
            a2.w += u0.w + u1.w + u2.w + u3.w;
        }
    }
    for (; i < cnt; ++i) {
        const float4* r0 = (const float4*)(hb + (size_t)lst[i] * HD);
        float4 v0 = r0[t];
        a0.x += v0.x; a0.y += v0.y; a0.z += v0.z; a0.w += v0.w;
        float4 w0 = r0[128 + t];
        a1.x += w0.x; a1.y += w0.y; a1.z += w0.z; a1.w += w0.w;
        if (t < 32) {
            float4 u0 = r0[256 + t];
            a2.x += u0.x; a2.y += u0.y; a2.z += u0.z; a2.w += u0.w;
        }
    }

    const float scale = 2.1213203435596424f;   // sqrt(1152) / 16
    const int orow = (b << 8) + (int)la + half;
    float4* o = (float4*)(out + (size_t)orow * HD);
    a0.x *= scale; a0.y *= scale; a0.z *= scale; a0.w *= scale;
    o[t] = a0;
    a1.x *= scale; a1.y *= scale; a1.z *= scale; a1.w *= scale;
    o[128 + t] = a1;
    if (t < 32) {
        a2.x *= scale; a2.y *= scale; a2.z *= scale; a2.w *= scale;
        o[256 + t] = a2;
    }
    if (t == 0) mask[orow] = (cnt > 0) ? 1.0f : 0.0f;
}

extern "C" void kernel_launch(void* const* d_in, const int* in_sizes, int n_in,
                              void* d_out, int out_size, void* d_ws, size_t ws_size,
                              hipStream_t stream) {
    const float* hs = (const float*)d_in[0];
    const int* pos = (const int*)d_in[1];
    float* out = (float*)d_out;                        // pooled [8,256,1152]
    float* mask = out + (size_t)BT * NB * HD;          // mask   [8,256]

    k_pool<<<BT * NB / 2, 256, 0, stream>>>(pos, hs, out, mask);
}